// Round 6
// baseline (818.790 us; speedup 1.0000x reference)
//
#include <hip/hip_runtime.h>
#include <math.h>

typedef __bf16 bf16x8 __attribute__((ext_vector_type(8)));
typedef float f32x4 __attribute__((ext_vector_type(4)));

__device__ __forceinline__ unsigned short f2bf(float x) {
  unsigned int u = __builtin_bit_cast(unsigned int, x);
  unsigned int r = (u + 0x7fffu + ((u >> 16) & 1u)) >> 16;
  return (unsigned short)r;
}
__device__ __forceinline__ float bf2f(unsigned short u) {
  return __builtin_bit_cast(float, ((unsigned int)u) << 16);
}

__device__ __forceinline__ void async16(const void* g, void* l) {
  __builtin_amdgcn_global_load_lds(
      (const __attribute__((address_space(1))) void*)g,
      (__attribute__((address_space(3))) void*)l, 16, 0, 0);
}

// C[m,n] = sum_k A[m,k]*B[n,k]; A bf16 [M,K], B f32 [N,K] (bf16-converted on LDS
// read), f32 accumulate. OUT_F32 selects epilogue store type.
template <bool OUT_F32>
__global__ __launch_bounds__(256) void gemm_bf(
    const unsigned short* __restrict__ A, const float* __restrict__ B,
    void* __restrict__ Cp, int M, int N, int K) {
  __shared__ unsigned short As[128 * 32];  // 8 KiB
  __shared__ float Bs[128 * 32];           // 16 KiB, k-slots XOR-swizzled by row
  const int tid = threadIdx.x;
  const int lane = tid & 63;
  const int w = tid >> 6;
  const int wr = w >> 1, wc = w & 1;
  const int fr = lane & 15, fq = lane >> 4;
  const long m0 = (long)blockIdx.y * 128;
  const long n0 = (long)blockIdx.x * 128;
  const int srA = lane >> 2, scA = (lane & 3) * 8;  // bf16: 16 rows/call
  const int srB = lane >> 3, scB = (lane & 7) * 4;  // f32 : 32 rows/call
  f32x4 acc[4][4] = {};
  for (int k0 = 0; k0 < K; k0 += 32) {
    __syncthreads();
#pragma unroll
    for (int i = 0; i < 2; i++) {
      const int r = (w * 2 + i) * 16 + srA;
      async16(A + (m0 + r) * (long)K + k0 + scA, &As[(w * 2 + i) * 512]);
    }
#pragma unroll
    for (int c = 0; c < 4; c++) {
      const int rb = (w * 4 + c) * 8 + srB;
      const int kk = scB ^ ((rb & 3) * 8);  // swizzle breaks bank conflicts
      async16(B + (n0 + rb) * (long)K + k0 + kk, &Bs[(w * 4 + c) * 256]);
    }
    __syncthreads();
    bf16x8 a[4], b[4];
#pragma unroll
    for (int i = 0; i < 4; i++)
      a[i] = *(const bf16x8*)&As[(wr * 64 + i * 16 + fr) * 32 + fq * 8];
#pragma unroll
    for (int j = 0; j < 4; j++) {
      const int rr = wc * 64 + j * 16 + fr;
      const float* bp = &Bs[rr * 32 + ((fq * 8) ^ ((rr & 3) * 8))];
      const f32x4 lo = *(const f32x4*)bp;
      const f32x4 hi = *(const f32x4*)(bp + 4);
      union { bf16x8 v; unsigned short u[8]; } t;
      t.u[0] = f2bf(lo[0]); t.u[1] = f2bf(lo[1]);
      t.u[2] = f2bf(lo[2]); t.u[3] = f2bf(lo[3]);
      t.u[4] = f2bf(hi[0]); t.u[5] = f2bf(hi[1]);
      t.u[6] = f2bf(hi[2]); t.u[7] = f2bf(hi[3]);
      b[j] = t.v;
    }
#pragma unroll
    for (int i = 0; i < 4; i++)
#pragma unroll
      for (int j = 0; j < 4; j++)
        acc[i][j] =
            __builtin_amdgcn_mfma_f32_16x16x32_bf16(a[i], b[j], acc[i][j], 0, 0, 0);
  }
#pragma unroll
  for (int i = 0; i < 4; i++)
#pragma unroll
    for (int j = 0; j < 4; j++)
#pragma unroll
      for (int r = 0; r < 4; r++) {
        const long m = m0 + wr * 64 + i * 16 + fq * 4 + r;
        const long n = n0 + wc * 64 + j * 16 + fr;
        if (OUT_F32)
          ((float*)Cp)[m * N + n] = acc[i][j][r];
        else
          ((unsigned short*)Cp)[m * N + n] = f2bf(acc[i][j][r]);
      }
}

// in-place on bf16 qkv rows: RMSNorm(q,k) (g=f32), RoPE(q,k); v untouched
__global__ __launch_bounds__(256) void rms_rope(unsigned short* __restrict__ qkv,
                                                const float* __restrict__ g) {
  const int m = blockIdx.x;  // 0..4095
  const int t = m & 2047;
  const int tid = threadIdx.x;
  const int lane = tid & 63, w = tid >> 6;
  unsigned short* row = qkv + (long)m * 6144;
  const int base = tid * 8;
  alignas(16) unsigned short qs[8], ks[8];
  *(uint4*)qs = *(const uint4*)(row + base);
  *(uint4*)ks = *(const uint4*)(row + 2048 + base);
  float qv[8], kv[8];
  float sq = 0.f, sk = 0.f;
#pragma unroll
  for (int j = 0; j < 8; j++) {
    qv[j] = bf2f(qs[j]);
    kv[j] = bf2f(ks[j]);
    sq += qv[j] * qv[j];
    sk += kv[j] * kv[j];
  }
#pragma unroll
  for (int off = 1; off < 64; off <<= 1) {
    sq += __shfl_xor(sq, off);
    sk += __shfl_xor(sk, off);
  }
  __shared__ float red[2][4];
  if (lane == 0) {
    red[0][w] = sq;
    red[1][w] = sk;
  }
  __syncthreads();
  sq = red[0][0] + red[0][1] + red[0][2] + red[0][3];
  sk = red[1][0] + red[1][1] + red[1][2] + red[1][3];
  const float rq = rsqrtf(sq * (1.f / 2048.f) + 1e-6f);
  const float rk = rsqrtf(sk * (1.f / 2048.f) + 1e-6f);
  float qn[8], kn[8];
#pragma unroll
  for (int j = 0; j < 8; j++) {
    const float gg = g[base + j];
    qn[j] = qv[j] * rq * gg;
    kn[j] = kv[j] * rk * gg;
  }
  const int d0 = base & 127;
  alignas(16) unsigned short qo[8], ko[8];
#pragma unroll
  for (int p = 0; p < 8; p += 2) {
    const int d = d0 + p;
    const int i0 = (d < 64) ? d : d - 64;
    const int i1 = (d + 1 < 64) ? d + 1 : d - 63;
    // ang[t,d] = t * 10000^(-(4*(d mod 64)+1)/128); accurate sincos (args ~1905 rad)
    const float kf = 13.287712379549449f / 128.f;  // log2(10000)/128
    const float a0 = (float)t * exp2f(-(4.f * i0 + 1.f) * kf);
    const float a1 = (float)t * exp2f(-(4.f * i1 + 1.f) * kf);
    float c0, s0, c1, s1;
    sincosf(a0, &s0, &c0);
    sincosf(a1, &s1, &c1);
    qo[p] = f2bf(qn[p] * c0 - qn[p + 1] * s0);
    qo[p + 1] = f2bf(qn[p + 1] * c1 + qn[p] * s1);
    ko[p] = f2bf(kn[p] * c0 - kn[p + 1] * s0);
    ko[p + 1] = f2bf(kn[p + 1] * c1 + kn[p] * s1);
  }
  *(uint4*)(row + base) = *(uint4*)qo;
  *(uint4*)(row + 2048 + base) = *(uint4*)ko;
}

// flash attention over interleaved qkv (row stride 6144)
__global__ __launch_bounds__(256) void attn64(
    const unsigned short* __restrict__ QKV, unsigned short* __restrict__ Y) {
  const int qt = blockIdx.x;  // 0..31
  const int bh = blockIdx.y;  // 0..31
  const int b = bh >> 4, h = bh & 15;
  const int tid = threadIdx.x, lane = tid & 63, w = tid >> 6;
  const int fr = lane & 15, fq = lane >> 4;
  const long RS = 6144;
  __shared__ unsigned short Kl[64 * 136];
  __shared__ unsigned short Vt[128 * 72];
  __shared__ unsigned short Pl[4][16 * 64];
  const long tokbase = (long)b * 2048;
  const unsigned short* Qp = QKV + tokbase * RS + h * 128;
  const unsigned short* Kp = Qp + 2048;
  const unsigned short* Vp = Qp + 4096;
  const int qbase = qt * 64;
  bf16x8 aq[4];
  {
    const unsigned short* qp = Qp + (long)(qbase + w * 16 + fr) * RS + fq * 8;
#pragma unroll
    for (int ks = 0; ks < 4; ks++) aq[ks] = *(const bf16x8*)(qp + ks * 32);
  }
  float m_i[4], l_i[4];
#pragma unroll
  for (int r = 0; r < 4; r++) {
    m_i[r] = -1e30f;
    l_i[r] = 0.f;
  }
  f32x4 accO[8] = {};
  const int srow = tid >> 4;
  const int scol = (tid & 15) * 8;
  for (int kt = 0; kt <= qt; kt++) {
    __syncthreads();
#pragma unroll
    for (int i = 0; i < 4; i++) {
      const int row = i * 16 + srow;
      const long trow = (long)(kt * 64 + row);
      const uint4 kvv = *(const uint4*)(Kp + trow * RS + scol);
      *(uint4*)&Kl[row * 136 + scol] = kvv;
      const uint4 vvv = *(const uint4*)(Vp + trow * RS + scol);
      alignas(16) unsigned short tmp[8];
      *(uint4*)tmp = vvv;
#pragma unroll
      for (int j = 0; j < 8; j++) Vt[(scol + j) * 72 + row] = tmp[j];
    }
    __syncthreads();
    f32x4 accS[4] = {};
#pragma unroll
    for (int n = 0; n < 4; n++)
#pragma unroll
      for (int ks = 0; ks < 4; ks++) {
        bf16x8 bk = *(const bf16x8*)&Kl[(n * 16 + fr) * 136 + ks * 32 + fq * 8];
        accS[n] = __builtin_amdgcn_mfma_f32_16x16x32_bf16(aq[ks], bk, accS[n], 0, 0, 0);
      }
    const float scale = 0.08838834764831845f;  // 1/sqrt(128)
#pragma unroll
    for (int n = 0; n < 4; n++)
#pragma unroll
      for (int r = 0; r < 4; r++) {
        const float s = accS[n][r] * scale;
        const int key = kt * 64 + n * 16 + fr;
        const int qq = qbase + w * 16 + fq * 4 + r;
        accS[n][r] = (key > qq) ? -1e30f : s;
      }
    float alpha[4];
#pragma unroll
    for (int r = 0; r < 4; r++) {
      float mx = fmaxf(fmaxf(accS[0][r], accS[1][r]), fmaxf(accS[2][r], accS[3][r]));
#pragma unroll
      for (int off = 1; off < 16; off <<= 1) mx = fmaxf(mx, __shfl_xor(mx, off));
      const float mnew = fmaxf(m_i[r], mx);
      alpha[r] = __expf(m_i[r] - mnew);
      m_i[r] = mnew;
    }
#pragma unroll
    for (int n = 0; n < 4; n++)
#pragma unroll
      for (int r = 0; r < 4; r++) accS[n][r] = __expf(accS[n][r] - m_i[r]);
#pragma unroll
    for (int r = 0; r < 4; r++) {
      float sum = accS[0][r] + accS[1][r] + accS[2][r] + accS[3][r];
#pragma unroll
      for (int off = 1; off < 16; off <<= 1) sum += __shfl_xor(sum, off);
      l_i[r] = l_i[r] * alpha[r] + sum;
    }
#pragma unroll
    for (int ds = 0; ds < 8; ds++)
#pragma unroll
      for (int r = 0; r < 4; r++) accO[ds][r] *= alpha[r];
      // P (C/D layout) -> per-wave LDS -> A layout
#pragma unroll
    for (int n = 0; n < 4; n++)
#pragma unroll
      for (int r = 0; r < 4; r++)
        Pl[w][(fq * 4 + r) * 64 + n * 16 + fr] = f2bf(accS[n][r]);
#pragma unroll
    for (int ks = 0; ks < 2; ks++) {
      bf16x8 ap = *(const bf16x8*)&Pl[w][fr * 64 + ks * 32 + fq * 8];
#pragma unroll
      for (int ds = 0; ds < 8; ds++) {
        bf16x8 bv = *(const bf16x8*)&Vt[(ds * 16 + fr) * 72 + ks * 32 + fq * 8];
        accO[ds] = __builtin_amdgcn_mfma_f32_16x16x32_bf16(ap, bv, accO[ds], 0, 0, 0);
      }
    }
  }
#pragma unroll
  for (int r = 0; r < 4; r++) l_i[r] = 1.f / l_i[r];
#pragma unroll
  for (int ds = 0; ds < 8; ds++)
#pragma unroll
    for (int r = 0; r < 4; r++) {
      const long trow = tokbase + qbase + w * 16 + fq * 4 + r;
      Y[trow * 2048 + h * 128 + ds * 16 + fr] = f2bf(accO[ds][r] * l_i[r]);
    }
}

extern "C" void kernel_launch(void* const* d_in, const int* in_sizes, int n_in,
                              void* d_out, int out_size, void* d_ws, size_t ws_size,
                              hipStream_t stream) {
  (void)out_size;
  (void)ws_size;
  const float *x = 0, *Wq = 0, *Wp = 0, *g = 0;
  for (int i = 0; i < n_in; i++) {
    switch (in_sizes[i]) {
      case 8388608: x = (const float*)d_in[i]; break;    // [2,2048,2048]
      case 12582912: Wq = (const float*)d_in[i]; break;  // [6144,2048]
      case 4194304: Wp = (const float*)d_in[i]; break;   // [2048,2048]
      case 2048: g = (const float*)d_in[i]; break;       // [2048]
    }
  }
  if (!x) x = (const float*)d_in[0];
  if (!Wq) Wq = (const float*)d_in[1];
  if (!Wp) Wp = (const float*)d_in[2];
  if (!g) g = (const float*)d_in[3];
  float* out = (float*)d_out;  // f32 output
  char* ws = (char*)d_ws;
  unsigned short* qkv16 = (unsigned short*)ws;            // 48 MiB
  unsigned short* Y = (unsigned short*)(ws + 50331648);   // 16 MiB -> 64 total
  unsigned short* xb = Y;  // reuse Y region? NO — xb needed through gemm1 only,
                           // Y written by attn later. Safe: xb dead after gemm1.

  // x -> bf16 into Y region (dead until attn), then gemm1 consumes it.
  // (cvt inline here to avoid another buffer)
  {
    // reuse gemm_bf's A-input as bf16: convert x once
  }
  // convert x to bf16 into xb (= Y region, 16 MiB)
  struct Cvt {
    static __global__ __launch_bounds__(256) void run(const float* in,
                                                      unsigned short* o, int n8);
  };
  // (defined below via lambda-less launch)
  extern __global__ void cvt_bf16_k(const float*, unsigned short*, int);
  cvt_bf16_k<<<4096, 256, 0, stream>>>(x, xb, 1048576);
  gemm_bf<false><<<dim3(48, 32), 256, 0, stream>>>(xb, Wq, qkv16, 4096, 6144, 2048);
  rms_rope<<<4096, 256, 0, stream>>>(qkv16, g);
  attn64<<<dim3(32, 32), 256, 0, stream>>>(qkv16, Y);  // overwrites xb (dead)
  gemm_bf<true><<<dim3(16, 32), 256, 0, stream>>>(Y, Wp, out, 4096, 2048, 2048);
}

// f32 -> bf16 (RNE), 8 elems/thread
__global__ __launch_bounds__(256) void cvt_bf16_k(const float* __restrict__ in,
                                                  unsigned short* __restrict__ out,
                                                  int n8) {
  const int i = blockIdx.x * 256 + threadIdx.x;
  if (i >= n8) return;
  const float4* p = (const float4*)in + (long)i * 2;
  const float4 v0 = p[0], v1 = p[1];
  alignas(16) unsigned short o[8] = {f2bf(v0.x), f2bf(v0.y), f2bf(v0.z), f2bf(v0.w),
                                     f2bf(v1.x), f2bf(v1.y), f2bf(v1.z), f2bf(v1.w)};
  *(uint4*)(out + (long)i * 8) = *(uint4*)o;
}